// Round 2
// baseline (351.759 us; speedup 1.0000x reference)
//
#include <hip/hip_runtime.h>
#include <math.h>

#define MGT 32
#define NCLS 80
#define TEPS 1e-9f
#define CEPS 1e-7f

__device__ __forceinline__ float ciou_f(float ax1, float ay1, float ax2, float ay2,
                                        float bx1, float by1, float bx2, float by2) {
    // matches reference _ciou (b1 = a, b2 = b); bit-symmetric in (a,b)
    float w1 = ax2 - ax1, h1 = ay2 - ay1;
    float w2 = bx2 - bx1, h2 = by2 - by1;
    float iw = fmaxf(fminf(ax2, bx2) - fmaxf(ax1, bx1), 0.f);
    float ih = fmaxf(fminf(ay2, by2) - fmaxf(ay1, by1), 0.f);
    float inter = iw * ih;
    float uni = w1 * h1 + w2 * h2 - inter + CEPS;
    float iou = inter / uni;
    float cw = fmaxf(ax2, bx2) - fminf(ax1, bx1);
    float ch = fmaxf(ay2, by2) - fminf(ay1, by1);
    float c2 = cw * cw + ch * ch + CEPS;
    float dx = bx1 + bx2 - ax1 - ax2;
    float dy = by1 + by2 - ay1 - ay2;
    float rho2 = (dx * dx + dy * dy) * 0.25f;
    float dv = atanf(w2 / (h2 + CEPS)) - atanf(w1 / (h1 + CEPS));
    float v = 0.405284734569351f * dv * dv;  // 4/pi^2
    float alpha = v / (v - iou + (1.f + CEPS));
    return iou - (rho2 / c2 + v * alpha);
}

__device__ __forceinline__ float sigm(float x) { return 1.f / (1.f + expf(-x)); }

// ---- kernel: best gt per anchor = argmax_m clip(ciou,0), first-max tiebreak ----
__global__ __launch_bounds__(256) void k_best(const float* __restrict__ bdec,
                                              const float* __restrict__ tgt,
                                              int* __restrict__ bestm, int Nv) {
    __shared__ float sx1[MGT], sy1[MGT], sx2[MGT], sy2[MGT];
    int b = blockIdx.y, tid = threadIdx.x;
    if (tid < MGT) {
        const float* t = tgt + ((size_t)b * MGT + tid) * 5;
        sx1[tid] = t[1]; sy1[tid] = t[2]; sx2[tid] = t[3]; sy2[tid] = t[4];
    }
    __syncthreads();
    int n = blockIdx.x * 256 + tid;
    if (n >= Nv) return;
    size_t bn = (size_t)b * Nv + n;
    float4 p = reinterpret_cast<const float4*>(bdec)[bn];
    float bo = -1.f; int bi = 0;
    for (int m = 0; m < MGT; ++m) {
        float ov = fmaxf(ciou_f(sx1[m], sy1[m], sx2[m], sy2[m], p.x, p.y, p.z, p.w), 0.f);
        if (ov > bo) { bo = ov; bi = m; }
    }
    bestm[bn] = bi;
}

// ---- kernel: align metric for a chunk of gts, written to ws ----
__global__ __launch_bounds__(256) void k_alignc(const float* __restrict__ cls,
                                                const float* __restrict__ bdec,
                                                const float* __restrict__ tgt,
                                                const float* __restrict__ anc,
                                                float* __restrict__ abuf,
                                                int cs, int clen, int Nv) {
    __shared__ float sx1[MGT], sy1[MGT], sx2[MGT], sy2[MGT];
    __shared__ int slab[MGT], svld[MGT];
    int b = blockIdx.y, tid = threadIdx.x;
    if (tid < MGT) {
        const float* t = tgt + ((size_t)b * MGT + tid) * 5;
        float lf = t[0];
        float x1 = t[1], y1 = t[2], x2 = t[3], y2 = t[4];
        sx1[tid] = x1; sy1[tid] = y1; sx2[tid] = x2; sy2[tid] = y2;
        float area = fmaxf(x2 - x1, 0.f) * fmaxf(y2 - y1, 0.f);
        int lab = (int)lf;
        svld[tid] = (lab >= 0 && area > 0.f) ? 1 : 0;
        slab[tid] = lab < 0 ? 0 : lab;
    }
    __syncthreads();
    int n = blockIdx.x * 256 + tid;
    if (n >= Nv) return;
    size_t bn = (size_t)b * Nv + n;
    float4 p = reinterpret_cast<const float4*>(bdec)[bn];
    float2 a = reinterpret_cast<const float2*>(anc)[n];
    const float* crow = cls + bn * NCLS;
    for (int mm = 0; mm < clen; ++mm) {
        int m = cs + mm;
        float al = 0.f;
        if (svld[m]) {
            float mn = fminf(fminf(a.x - sx1[m], a.y - sy1[m]),
                             fminf(sx2[m] - a.x, sy2[m] - a.y));
            if (mn > TEPS) {
                float ov = fmaxf(ciou_f(sx1[m], sy1[m], sx2[m], sy2[m],
                                        p.x, p.y, p.z, p.w), 0.f);
                if (ov > 0.f) {
                    float s = sigm(crow[slab[m]]);
                    float o2 = ov * ov;
                    al = sqrtf(s) * o2 * o2 * o2;  // s^0.5 * ov^6
                }
            }
        }
        abuf[((size_t)b * clen + mm) * Nv + n] = al;
    }
}

// ---- kernel: per-(b,m) top-10 over N, set bit m in selmask for winners > EPS ----
__global__ __launch_bounds__(256) void k_topk(const float* __restrict__ abuf,
                                              unsigned* __restrict__ selmask,
                                              int cs, int clen, int Nv) {
    __shared__ float lv[2560];
    __shared__ int li[2560];
    __shared__ float rv[256];
    __shared__ int ri[256];
    int bmi = blockIdx.x;
    int b = bmi / clen, mm = bmi % clen;
    int m = cs + mm;
    int tid = threadIdx.x;
    const float* row = abuf + ((size_t)b * clen + mm) * Nv;
    float v[10]; int ix[10];
#pragma unroll
    for (int i = 0; i < 10; ++i) { v[i] = -1.f; ix[i] = 0x7fffffff; }
    for (int n = tid; n < Nv; n += 256) {
        float aa = row[n];
        if (aa > v[0]) {  // sorted ascending; equal -> keep earlier (lower idx)
            float cv = aa; int ci = n; bool placed = false;
#pragma unroll
            for (int i = 0; i < 9; ++i) {
                if (!placed) {
                    if (cv > v[i + 1]) { v[i] = v[i + 1]; ix[i] = ix[i + 1]; }
                    else { v[i] = cv; ix[i] = ci; placed = true; }
                }
            }
            if (!placed) { v[9] = cv; ix[9] = ci; }
        }
    }
#pragma unroll
    for (int i = 0; i < 10; ++i) { lv[tid * 10 + i] = v[i]; li[tid * 10 + i] = ix[i]; }
    int p = 9;
    for (int r = 0; r < 10; ++r) {
        float cv = (p >= 0) ? lv[tid * 10 + p] : -2.f;
        int ci = (p >= 0) ? li[tid * 10 + p] : -1;
        rv[tid] = cv; ri[tid] = ci;
        __syncthreads();
        for (int s = 128; s > 0; s >>= 1) {
            if (tid < s) {
                float o = rv[tid + s]; int oi = ri[tid + s];
                if (o > rv[tid] || (o == rv[tid] && oi < ri[tid])) { rv[tid] = o; ri[tid] = oi; }
            }
            __syncthreads();
        }
        float wv = rv[0]; int wi = ri[0];
        if (p >= 0 && cv == wv && ci == wi) --p;  // unique owner: indices disjoint
        if (tid == 0 && wv > TEPS) atomicOr(&selmask[(size_t)b * Nv + wi], 1u << m);
        __syncthreads();
    }
}

// ---- kernel: resolve multi-assignment, store per-anchor gt/align/ciou, pos maxes ----
__global__ __launch_bounds__(256) void k_resolve(const float* __restrict__ cls,
                                                 const float* __restrict__ bdec,
                                                 const float* __restrict__ tgt,
                                                 const float* __restrict__ anc,
                                                 const unsigned* __restrict__ selmask,
                                                 const int* __restrict__ bestm,
                                                 int* __restrict__ gtf,
                                                 float* __restrict__ amv,
                                                 float* __restrict__ crv,
                                                 unsigned* __restrict__ pos_al,
                                                 unsigned* __restrict__ pos_ov, int Nv) {
    __shared__ float sx1[MGT], sy1[MGT], sx2[MGT], sy2[MGT];
    __shared__ int slab[MGT], svld[MGT];
    int b = blockIdx.y, tid = threadIdx.x;
    if (tid < MGT) {
        const float* t = tgt + ((size_t)b * MGT + tid) * 5;
        float lf = t[0];
        float x1 = t[1], y1 = t[2], x2 = t[3], y2 = t[4];
        sx1[tid] = x1; sy1[tid] = y1; sx2[tid] = x2; sy2[tid] = y2;
        float area = fmaxf(x2 - x1, 0.f) * fmaxf(y2 - y1, 0.f);
        int lab = (int)lf;
        svld[tid] = (lab >= 0 && area > 0.f) ? 1 : 0;
        slab[tid] = lab < 0 ? 0 : lab;
    }
    __syncthreads();
    int n = blockIdx.x * 256 + tid;
    if (n >= Nv) return;
    size_t bn = (size_t)b * Nv + n;
    unsigned msk = selmask[bn];
    if (__popc(msk) > 1) msk = 1u << bestm[bn];  // multi -> is_best (unmasked argmax)
    if (!msk) { gtf[bn] = -1; amv[bn] = 0.f; crv[bn] = 0.f; return; }
    int g = __ffs(msk) - 1;
    float4 p = reinterpret_cast<const float4*>(bdec)[bn];
    float cr = ciou_f(sx1[g], sy1[g], sx2[g], sy2[g], p.x, p.y, p.z, p.w);
    float ov = fmaxf(cr, 0.f);
    float al = 0.f;
    if (svld[g]) {
        float2 a = reinterpret_cast<const float2*>(anc)[n];
        float mn = fminf(fminf(a.x - sx1[g], a.y - sy1[g]),
                         fminf(sx2[g] - a.x, sy2[g] - a.y));
        if (mn > TEPS && ov > 0.f) {
            float s = sigm(cls[bn * NCLS + slab[g]]);
            float o2 = ov * ov;
            al = sqrtf(s) * o2 * o2 * o2;
        }
    }
    gtf[bn] = g; amv[bn] = al; crv[bn] = cr;
    // nonneg floats: uint compare == float compare
    atomicMax(&pos_al[b * MGT + g], __float_as_uint(al));
    atomicMax(&pos_ov[b * MGT + g], __float_as_uint(ov));
}

// ---- kernel: norm (tval), tss, IoU loss, DFL loss partials ----
__global__ __launch_bounds__(256) void k_boxdfl(const float* __restrict__ bdist,
                                                const float* __restrict__ tgt,
                                                const float* __restrict__ anc,
                                                const float* __restrict__ strd,
                                                const int* __restrict__ gtf,
                                                const float* __restrict__ amv,
                                                const float* __restrict__ crv,
                                                const unsigned* __restrict__ pos_al,
                                                const unsigned* __restrict__ pos_ov,
                                                float* __restrict__ tval,
                                                float* __restrict__ p_tss,
                                                float* __restrict__ p_iou,
                                                float* __restrict__ p_dfl, int Nv) {
    __shared__ float sx1[MGT], sy1[MGT], sx2[MGT], sy2[MGT];
    __shared__ float r0[256], r1[256], r2[256];
    int b = blockIdx.y, tid = threadIdx.x;
    if (tid < MGT) {
        const float* t = tgt + ((size_t)b * MGT + tid) * 5;
        sx1[tid] = t[1]; sy1[tid] = t[2]; sx2[tid] = t[3]; sy2[tid] = t[4];
    }
    __syncthreads();
    int n = blockIdx.x * 256 + tid;
    float c_t = 0.f, c_i = 0.f, c_d = 0.f;
    if (n < Nv) {
        size_t bn = (size_t)b * Nv + n;
        int g = gtf[bn];
        float nv = 0.f;
        if (g >= 0) {
            float pa = __uint_as_float(pos_al[b * MGT + g]);
            float po = __uint_as_float(pos_ov[b * MGT + g]);
            nv = amv[bn] * po / (pa + TEPS);
        }
        tval[bn] = nv;
        if (nv > 0.f) {
            c_t = nv;
            c_i = (1.f - crv[bn]) * nv;
            float2 a = reinterpret_cast<const float2*>(anc)[n];
            float st = strd[n];
            float ttv[4];
            ttv[0] = (a.x - sx1[g]) / st;
            ttv[1] = (a.y - sy1[g]) / st;
            ttv[2] = (sx2[g] - a.x) / st;
            ttv[3] = (sy2[g] - a.y) / st;
            const float* bd = bdist + bn * 64;
            float acc = 0.f;
#pragma unroll
            for (int k = 0; k < 4; ++k) {
                float t = fminf(fmaxf(ttv[k], 0.f), 14.99f);
                int tl = (int)t;
                float wl = (float)(tl + 1) - t;
                float mx = -3.4e38f;
                for (int j = 0; j < 16; ++j) mx = fmaxf(mx, bd[k * 16 + j]);
                float se = 0.f;
                for (int j = 0; j < 16; ++j) se += expf(bd[k * 16 + j] - mx);
                float lse = mx + logf(se);
                float ll = bd[k * 16 + tl] - lse;
                float lr = bd[k * 16 + tl + 1] - lse;
                acc += ll * wl + lr * (1.f - wl);
            }
            c_d = (-acc * 0.25f) * nv;
        }
    }
    r0[tid] = c_t; r1[tid] = c_i; r2[tid] = c_d;
    __syncthreads();
    for (int s = 128; s > 0; s >>= 1) {
        if (tid < s) { r0[tid] += r0[tid + s]; r1[tid] += r1[tid + s]; r2[tid] += r2[tid + s]; }
        __syncthreads();
    }
    if (tid == 0) {
        int bi = blockIdx.y * gridDim.x + blockIdx.x;
        p_tss[bi] = r0[0]; p_iou[bi] = r1[0]; p_dfl[bi] = r2[0];
    }
}

// ---- kernel: BCE classification loss over all (B,N,C) ----
__global__ __launch_bounds__(256) void k_cls(const float* __restrict__ cls,
                                             const float* __restrict__ tgt,
                                             const int* __restrict__ gtf,
                                             const float* __restrict__ tval,
                                             float* __restrict__ p_cls, int Nv) {
    __shared__ int slab[MGT];
    __shared__ float rs[256];
    int b = blockIdx.y, tid = threadIdx.x;
    if (tid < MGT) {
        float lf = tgt[((size_t)b * MGT + tid) * 5];
        slab[tid] = lf < 0.f ? 0 : (int)lf;
    }
    __syncthreads();
    int n = blockIdx.x * 256 + tid;
    float sum = 0.f;
    if (n < Nv) {
        size_t bn = (size_t)b * Nv + n;
        int g = gtf[bn];
        float tv = tval[bn];
        int tlab = (g >= 0) ? slab[g] : -1;
        const float4* row = reinterpret_cast<const float4*>(cls + bn * NCLS);
        for (int j = 0; j < NCLS / 4; ++j) {
            float4 x4 = row[j];
            float xs[4] = {x4.x, x4.y, x4.z, x4.w};
#pragma unroll
            for (int e = 0; e < 4; ++e) {
                int c = j * 4 + e;
                float x = xs[e];
                float pv = sigm(x);
                float t = (c == tlab) ? tv : 0.f;
                float bce = fmaxf(x, 0.f) - x * t + log1pf(expf(-fabsf(x)));
                float w = (t > 0.f) ? t : 0.75f * pv * pv;
                sum += bce * w;
            }
        }
    }
    rs[tid] = sum;
    __syncthreads();
    for (int s = 128; s > 0; s >>= 1) {
        if (tid < s) rs[tid] += rs[tid + s];
        __syncthreads();
    }
    if (tid == 0) p_cls[blockIdx.y * gridDim.x + blockIdx.x] = rs[0];
}

// ---- kernel: deterministic final reduce + combine ----
__global__ __launch_bounds__(256) void k_final(const float* __restrict__ p_tss,
                                               const float* __restrict__ p_iou,
                                               const float* __restrict__ p_dfl,
                                               const float* __restrict__ p_cls,
                                               int nb, float* __restrict__ out, int Bv) {
    __shared__ float s0[256], s1[256], s2[256], s3[256];
    int tid = threadIdx.x;
    float a0 = 0.f, a1 = 0.f, a2 = 0.f, a3 = 0.f;
    for (int i = tid; i < nb; i += 256) {
        a0 += p_tss[i]; a1 += p_iou[i]; a2 += p_dfl[i]; a3 += p_cls[i];
    }
    s0[tid] = a0; s1[tid] = a1; s2[tid] = a2; s3[tid] = a3;
    __syncthreads();
    for (int s = 128; s > 0; s >>= 1) {
        if (tid < s) { s0[tid] += s0[tid + s]; s1[tid] += s1[tid + s];
                       s2[tid] += s2[tid + s]; s3[tid] += s3[tid + s]; }
        __syncthreads();
    }
    if (tid == 0) {
        float tss = fmaxf(s0[0], 1.f);
        float lcls = 0.5f * s3[0] / tss;
        float liou = 7.5f * s1[0] / tss;
        float ldfl = 1.5f * s2[0] / tss;
        out[0] = (lcls + liou + ldfl) * (float)Bv;
        out[1] = lcls;
        out[2] = liou;
        out[3] = ldfl;
    }
}

extern "C" void kernel_launch(void* const* d_in, const int* in_sizes, int n_in,
                              void* d_out, int out_size, void* d_ws, size_t ws_size,
                              hipStream_t stream) {
    const float* cls = (const float*)d_in[0];
    const float* bdist = (const float*)d_in[1];
    const float* bdec = (const float*)d_in[2];
    const float* tgt = (const float*)d_in[3];
    const float* anc = (const float*)d_in[4];
    const float* strd = (const float*)d_in[5];
    int Nv = in_sizes[4] / 2;
    int Bv = in_sizes[3] / (MGT * 5);
    size_t nBN = (size_t)Bv * Nv;
    int gx = (Nv + 255) / 256;
    int nb = gx * Bv;

    char* base = (char*)d_ws;
    size_t off = 0;
    unsigned* selmask = (unsigned*)(base + off); off += nBN * 4;
    unsigned* pos_al = (unsigned*)(base + off); off += (size_t)Bv * MGT * 4;
    unsigned* pos_ov = (unsigned*)(base + off); off += (size_t)Bv * MGT * 4;
    size_t zbytes = off;  // region needing zero-init each call
    int* bestm = (int*)(base + off); off += nBN * 4;
    int* gtfv = (int*)(base + off); off += nBN * 4;
    float* amv = (float*)(base + off); off += nBN * 4;
    float* crvv = (float*)(base + off); off += nBN * 4;
    float* tvalv = (float*)(base + off); off += nBN * 4;
    float* p_tss = (float*)(base + off); off += (size_t)nb * 4;
    float* p_iou = (float*)(base + off); off += (size_t)nb * 4;
    float* p_dfl = (float*)(base + off); off += (size_t)nb * 4;
    float* p_cls = (float*)(base + off); off += (size_t)nb * 4;
    float* abuf = (float*)(base + off);
    size_t remain = (ws_size > off) ? (ws_size - off) : 0;
    int chunk = (int)(remain / (nBN * 4));
    if (chunk > MGT) chunk = MGT;
    if (chunk < 1) chunk = 1;

    hipMemsetAsync(selmask, 0, zbytes, stream);
    dim3 grid(gx, Bv);
    k_best<<<grid, 256, 0, stream>>>(bdec, tgt, bestm, Nv);
    for (int cs = 0; cs < MGT; cs += chunk) {
        int clen = (MGT - cs < chunk) ? (MGT - cs) : chunk;
        k_alignc<<<grid, 256, 0, stream>>>(cls, bdec, tgt, anc, abuf, cs, clen, Nv);
        k_topk<<<Bv * clen, 256, 0, stream>>>(abuf, selmask, cs, clen, Nv);
    }
    k_resolve<<<grid, 256, 0, stream>>>(cls, bdec, tgt, anc, selmask, bestm,
                                        gtfv, amv, crvv, pos_al, pos_ov, Nv);
    k_boxdfl<<<grid, 256, 0, stream>>>(bdist, tgt, anc, strd, gtfv, amv, crvv,
                                       pos_al, pos_ov, tvalv, p_tss, p_iou, p_dfl, Nv);
    k_cls<<<grid, 256, 0, stream>>>(cls, tgt, gtfv, tvalv, p_cls, Nv);
    k_final<<<1, 256, 0, stream>>>(p_tss, p_iou, p_dfl, p_cls, nb, (float*)d_out, Bv);
}

// Round 6
// 210.872 us; speedup vs baseline: 1.6681x; 1.6681x over previous
//
#include <hip/hip_runtime.h>
#include <math.h>

#define MGT 32
#define NCLS 80
#define TEPS 1e-9f
#define CEPS 1e-7f

__device__ __forceinline__ float ciou_f(float ax1, float ay1, float ax2, float ay2,
                                        float bx1, float by1, float bx2, float by2) {
    // matches reference _ciou (b1 = a, b2 = b); bit-symmetric in (a,b)
    float w1 = ax2 - ax1, h1 = ay2 - ay1;
    float w2 = bx2 - bx1, h2 = by2 - by1;
    float iw = fmaxf(fminf(ax2, bx2) - fmaxf(ax1, bx1), 0.f);
    float ih = fmaxf(fminf(ay2, by2) - fmaxf(ay1, by1), 0.f);
    float inter = iw * ih;
    float uni = w1 * h1 + w2 * h2 - inter + CEPS;
    float iou = inter / uni;
    float cw = fmaxf(ax2, bx2) - fminf(ax1, bx1);
    float ch = fmaxf(ay2, by2) - fminf(ay1, by1);
    float c2 = cw * cw + ch * ch + CEPS;
    float dx = bx1 + bx2 - ax1 - ax2;
    float dy = by1 + by2 - ay1 - ay2;
    float rho2 = (dx * dx + dy * dy) * 0.25f;
    float dv = atanf(w2 / (h2 + CEPS)) - atanf(w1 / (h1 + CEPS));
    float v = 0.405284734569351f * dv * dv;  // 4/pi^2
    float alpha = v / (v - iou + (1.f + CEPS));
    return iou - (rho2 / c2 + v * alpha);
}

__device__ __forceinline__ float sigm_fast(float x) {
    return __builtin_amdgcn_rcpf(1.f + __expf(-x));
}

// ---- kernel: best gt per anchor = argmax_m clip(ciou,0), first-max tiebreak ----
__global__ __launch_bounds__(256) void k_best(const float* __restrict__ bdec,
                                              const float* __restrict__ tgt,
                                              int* __restrict__ bestm, int Nv) {
    __shared__ float sx1[MGT], sy1[MGT], sx2[MGT], sy2[MGT];
    int b = blockIdx.y, tid = threadIdx.x;
    if (tid < MGT) {
        const float* t = tgt + ((size_t)b * MGT + tid) * 5;
        sx1[tid] = t[1]; sy1[tid] = t[2]; sx2[tid] = t[3]; sy2[tid] = t[4];
    }
    __syncthreads();
    int n = blockIdx.x * 256 + tid;
    if (n >= Nv) return;
    size_t bn = (size_t)b * Nv + n;
    float4 p = reinterpret_cast<const float4*>(bdec)[bn];
    float bo = -1.f; int bi = 0;
    for (int m = 0; m < MGT; ++m) {
        float ov = fmaxf(ciou_f(sx1[m], sy1[m], sx2[m], sy2[m], p.x, p.y, p.z, p.w), 0.f);
        if (ov > bo) { bo = ov; bi = m; }
    }
    bestm[bn] = bi;
}

// ---- kernel: align metric for a chunk of gts, written to ws ----
__global__ __launch_bounds__(256) void k_alignc(const float* __restrict__ cls,
                                                const float* __restrict__ bdec,
                                                const float* __restrict__ tgt,
                                                const float* __restrict__ anc,
                                                float* __restrict__ abuf,
                                                int cs, int clen, int Nv) {
    __shared__ float sx1[MGT], sy1[MGT], sx2[MGT], sy2[MGT];
    __shared__ int slab[MGT], svld[MGT];
    int b = blockIdx.y, tid = threadIdx.x;
    if (tid < MGT) {
        const float* t = tgt + ((size_t)b * MGT + tid) * 5;
        float lf = t[0];
        float x1 = t[1], y1 = t[2], x2 = t[3], y2 = t[4];
        sx1[tid] = x1; sy1[tid] = y1; sx2[tid] = x2; sy2[tid] = y2;
        float area = fmaxf(x2 - x1, 0.f) * fmaxf(y2 - y1, 0.f);
        int lab = (int)lf;
        svld[tid] = (lab >= 0 && area > 0.f) ? 1 : 0;
        slab[tid] = lab < 0 ? 0 : lab;
    }
    __syncthreads();
    int n = blockIdx.x * 256 + tid;
    if (n >= Nv) return;
    size_t bn = (size_t)b * Nv + n;
    float4 p = reinterpret_cast<const float4*>(bdec)[bn];
    float2 a = reinterpret_cast<const float2*>(anc)[n];
    const float* crow = cls + bn * NCLS;
    for (int mm = 0; mm < clen; ++mm) {
        int m = cs + mm;
        float al = 0.f;
        if (svld[m]) {
            float mn = fminf(fminf(a.x - sx1[m], a.y - sy1[m]),
                             fminf(sx2[m] - a.x, sy2[m] - a.y));
            if (mn > TEPS) {
                float ov = fmaxf(ciou_f(sx1[m], sy1[m], sx2[m], sy2[m],
                                        p.x, p.y, p.z, p.w), 0.f);
                if (ov > 0.f) {
                    float s = sigm_fast(crow[slab[m]]);
                    float o2 = ov * ov;
                    al = __builtin_sqrtf(s) * o2 * o2 * o2;  // s^0.5 * ov^6
                }
            }
        }
        abuf[((size_t)b * clen + mm) * Nv + n] = al;
    }
}

// ---- kernel: per-(b,m) top-10 over N, set bit m in selmask for winners > EPS ----
__global__ __launch_bounds__(256) void k_topk(const float* __restrict__ abuf,
                                              unsigned* __restrict__ selmask,
                                              int cs, int clen, int Nv) {
    __shared__ float lv[2560];
    __shared__ int li[2560];
    __shared__ float rv[256];
    __shared__ int ri[256];
    int bmi = blockIdx.x;
    int b = bmi / clen, mm = bmi % clen;
    int m = cs + mm;
    int tid = threadIdx.x;
    const float* row = abuf + ((size_t)b * clen + mm) * Nv;
    float v[10]; int ix[10];
#pragma unroll
    for (int i = 0; i < 10; ++i) { v[i] = -1.f; ix[i] = 0x7fffffff; }
    for (int n = tid; n < Nv; n += 256) {
        float aa = row[n];
        if (aa > v[0]) {  // sorted ascending; equal -> keep earlier (lower idx)
            float cv = aa; int ci = n; bool placed = false;
#pragma unroll
            for (int i = 0; i < 9; ++i) {
                if (!placed) {
                    if (cv > v[i + 1]) { v[i] = v[i + 1]; ix[i] = ix[i + 1]; }
                    else { v[i] = cv; ix[i] = ci; placed = true; }
                }
            }
            if (!placed) { v[9] = cv; ix[9] = ci; }
        }
    }
#pragma unroll
    for (int i = 0; i < 10; ++i) { lv[tid * 10 + i] = v[i]; li[tid * 10 + i] = ix[i]; }
    int p = 9;
    for (int r = 0; r < 10; ++r) {
        float cv = (p >= 0) ? lv[tid * 10 + p] : -2.f;
        int ci = (p >= 0) ? li[tid * 10 + p] : -1;
        rv[tid] = cv; ri[tid] = ci;
        __syncthreads();
        for (int s = 128; s > 0; s >>= 1) {
            if (tid < s) {
                float o = rv[tid + s]; int oi = ri[tid + s];
                if (o > rv[tid] || (o == rv[tid] && oi < ri[tid])) { rv[tid] = o; ri[tid] = oi; }
            }
            __syncthreads();
        }
        float wv = rv[0]; int wi = ri[0];
        if (p >= 0 && cv == wv && ci == wi) --p;  // unique owner: indices disjoint
        if (tid == 0 && wv > TEPS) atomicOr(&selmask[(size_t)b * Nv + wi], 1u << m);
        __syncthreads();
    }
}

// ---- kernel: resolve multi-assignment, store per-anchor gt/align/ciou, pos maxes ----
__global__ __launch_bounds__(256) void k_resolve(const float* __restrict__ cls,
                                                 const float* __restrict__ bdec,
                                                 const float* __restrict__ tgt,
                                                 const float* __restrict__ anc,
                                                 const unsigned* __restrict__ selmask,
                                                 const int* __restrict__ bestm,
                                                 int* __restrict__ gtf,
                                                 float* __restrict__ amv,
                                                 float* __restrict__ crv,
                                                 unsigned* __restrict__ pos_al,
                                                 unsigned* __restrict__ pos_ov, int Nv) {
    __shared__ float sx1[MGT], sy1[MGT], sx2[MGT], sy2[MGT];
    __shared__ int slab[MGT], svld[MGT];
    int b = blockIdx.y, tid = threadIdx.x;
    if (tid < MGT) {
        const float* t = tgt + ((size_t)b * MGT + tid) * 5;
        float lf = t[0];
        float x1 = t[1], y1 = t[2], x2 = t[3], y2 = t[4];
        sx1[tid] = x1; sy1[tid] = y1; sx2[tid] = x2; sy2[tid] = y2;
        float area = fmaxf(x2 - x1, 0.f) * fmaxf(y2 - y1, 0.f);
        int lab = (int)lf;
        svld[tid] = (lab >= 0 && area > 0.f) ? 1 : 0;
        slab[tid] = lab < 0 ? 0 : lab;
    }
    __syncthreads();
    int n = blockIdx.x * 256 + tid;
    if (n >= Nv) return;
    size_t bn = (size_t)b * Nv + n;
    unsigned msk = selmask[bn];
    if (__popc(msk) > 1) msk = 1u << bestm[bn];  // multi -> is_best (unmasked argmax)
    if (!msk) { gtf[bn] = -1; amv[bn] = 0.f; crv[bn] = 0.f; return; }
    int g = __ffs(msk) - 1;
    float4 p = reinterpret_cast<const float4*>(bdec)[bn];
    float cr = ciou_f(sx1[g], sy1[g], sx2[g], sy2[g], p.x, p.y, p.z, p.w);
    float ov = fmaxf(cr, 0.f);
    float al = 0.f;
    if (svld[g]) {
        float2 a = reinterpret_cast<const float2*>(anc)[n];
        float mn = fminf(fminf(a.x - sx1[g], a.y - sy1[g]),
                         fminf(sx2[g] - a.x, sy2[g] - a.y));
        if (mn > TEPS && ov > 0.f) {
            float s = sigm_fast(cls[bn * NCLS + slab[g]]);
            float o2 = ov * ov;
            al = __builtin_sqrtf(s) * o2 * o2 * o2;
        }
    }
    gtf[bn] = g; amv[bn] = al; crv[bn] = cr;
    // nonneg floats: uint compare == float compare
    atomicMax(&pos_al[b * MGT + g], __float_as_uint(al));
    atomicMax(&pos_ov[b * MGT + g], __float_as_uint(ov));
}

// ---- kernel: norm (tval), tlab, tss, IoU loss, DFL loss partials ----
__global__ __launch_bounds__(256) void k_boxdfl(const float* __restrict__ bdist,
                                                const float* __restrict__ tgt,
                                                const float* __restrict__ anc,
                                                const float* __restrict__ strd,
                                                const int* __restrict__ gtf,
                                                const float* __restrict__ amv,
                                                const float* __restrict__ crv,
                                                const unsigned* __restrict__ pos_al,
                                                const unsigned* __restrict__ pos_ov,
                                                float* __restrict__ tval,
                                                int* __restrict__ tlabv,
                                                float* __restrict__ p_tss,
                                                float* __restrict__ p_iou,
                                                float* __restrict__ p_dfl, int Nv) {
    __shared__ float sx1[MGT], sy1[MGT], sx2[MGT], sy2[MGT];
    __shared__ int slab[MGT];
    __shared__ float r0[256], r1[256], r2[256];
    int b = blockIdx.y, tid = threadIdx.x;
    if (tid < MGT) {
        const float* t = tgt + ((size_t)b * MGT + tid) * 5;
        float lf = t[0];
        sx1[tid] = t[1]; sy1[tid] = t[2]; sx2[tid] = t[3]; sy2[tid] = t[4];
        slab[tid] = lf < 0.f ? 0 : (int)lf;
    }
    __syncthreads();
    int n = blockIdx.x * 256 + tid;
    float c_t = 0.f, c_i = 0.f, c_d = 0.f;
    if (n < Nv) {
        size_t bn = (size_t)b * Nv + n;
        int g = gtf[bn];
        float nv = 0.f;
        if (g >= 0) {
            float pa = __uint_as_float(pos_al[b * MGT + g]);
            float po = __uint_as_float(pos_ov[b * MGT + g]);
            nv = amv[bn] * po / (pa + TEPS);
        }
        tval[bn] = nv;
        tlabv[bn] = (g >= 0) ? slab[g] : -1;
        if (nv > 0.f) {
            c_t = nv;
            c_i = (1.f - crv[bn]) * nv;
            float2 a = reinterpret_cast<const float2*>(anc)[n];
            float st = strd[n];
            float ttv[4];
            ttv[0] = (a.x - sx1[g]) / st;
            ttv[1] = (a.y - sy1[g]) / st;
            ttv[2] = (sx2[g] - a.x) / st;
            ttv[3] = (sy2[g] - a.y) / st;
            const float* bd = bdist + bn * 64;
            float acc = 0.f;
#pragma unroll
            for (int k = 0; k < 4; ++k) {
                float t = fminf(fmaxf(ttv[k], 0.f), 14.99f);
                int tl = (int)t;
                float wl = (float)(tl + 1) - t;
                float mx = -3.4e38f;
                for (int j = 0; j < 16; ++j) mx = fmaxf(mx, bd[k * 16 + j]);
                float se = 0.f;
                for (int j = 0; j < 16; ++j) se += __expf(bd[k * 16 + j] - mx);
                float lse = mx + __logf(se);
                float ll = bd[k * 16 + tl] - lse;
                float lr = bd[k * 16 + tl + 1] - lse;
                acc += ll * wl + lr * (1.f - wl);
            }
            c_d = (-acc * 0.25f) * nv;
        }
    }
    r0[tid] = c_t; r1[tid] = c_i; r2[tid] = c_d;
    __syncthreads();
    for (int s = 128; s > 0; s >>= 1) {
        if (tid < s) { r0[tid] += r0[tid + s]; r1[tid] += r1[tid + s]; r2[tid] += r2[tid + s]; }
        __syncthreads();
    }
    if (tid == 0) {
        int bi = blockIdx.y * gridDim.x + blockIdx.x;
        p_tss[bi] = r0[0]; p_iou[bi] = r1[0]; p_dfl[bi] = r2[0];
    }
}

// ---- kernel: BCE classification loss, flat-linear coalesced, fast math ----
__global__ __launch_bounds__(256) void k_cls2(const float* __restrict__ cls,
                                              const int* __restrict__ tlabv,
                                              const float* __restrict__ tval,
                                              float* __restrict__ p_cls,
                                              long long total4, int stride_t) {
    __shared__ float rs[256];
    float sum = 0.f;
    for (long long i4 = (long long)blockIdx.x * 256 + threadIdx.x; i4 < total4;
         i4 += stride_t) {
        long long bn = i4 / 20;  // 20 float4 per 80-class row
        int pos = (int)(i4 - bn * 20);
        float4 x4 = reinterpret_cast<const float4*>(cls)[i4];
        int tlab = tlabv[bn];
        float tv = tval[bn];
        int c0 = pos * 4;
        float xs[4] = {x4.x, x4.y, x4.z, x4.w};
#pragma unroll
        for (int e = 0; e < 4; ++e) {
            float x = xs[e];
            float ea = __expf(-fabsf(x));        // shared: sigmoid + log1p
            float r = __builtin_amdgcn_rcpf(1.f + ea);
            float p = (x >= 0.f) ? r : ea * r;   // sigmoid(x)
            float t = (c0 + e == tlab) ? tv : 0.f;
            float bce = fmaxf(x, 0.f) - x * t + __logf(1.f + ea);
            float w = (t > 0.f) ? t : 0.75f * p * p;
            sum += bce * w;
        }
    }
    rs[threadIdx.x] = sum;
    __syncthreads();
    for (int s = 128; s > 0; s >>= 1) {
        if (threadIdx.x < s) rs[threadIdx.x] += rs[threadIdx.x + s];
        __syncthreads();
    }
    if (threadIdx.x == 0) p_cls[blockIdx.x] = rs[0];
}

// ---- kernel: deterministic final reduce + combine ----
__global__ __launch_bounds__(256) void k_final(const float* __restrict__ p_tss,
                                               const float* __restrict__ p_iou,
                                               const float* __restrict__ p_dfl,
                                               int nb,
                                               const float* __restrict__ p_cls,
                                               int ncb, float* __restrict__ out, int Bv) {
    __shared__ float s0[256], s1[256], s2[256], s3[256];
    int tid = threadIdx.x;
    float a0 = 0.f, a1 = 0.f, a2 = 0.f, a3 = 0.f;
    for (int i = tid; i < nb; i += 256) {
        a0 += p_tss[i]; a1 += p_iou[i]; a2 += p_dfl[i];
    }
    for (int i = tid; i < ncb; i += 256) a3 += p_cls[i];
    s0[tid] = a0; s1[tid] = a1; s2[tid] = a2; s3[tid] = a3;
    __syncthreads();
    for (int s = 128; s > 0; s >>= 1) {
        if (tid < s) { s0[tid] += s0[tid + s]; s1[tid] += s1[tid + s];
                       s2[tid] += s2[tid + s]; s3[tid] += s3[tid + s]; }
        __syncthreads();
    }
    if (tid == 0) {
        float tss = fmaxf(s0[0], 1.f);
        float lcls = 0.5f * s3[0] / tss;
        float liou = 7.5f * s1[0] / tss;
        float ldfl = 1.5f * s2[0] / tss;
        out[0] = (lcls + liou + ldfl) * (float)Bv;
        out[1] = lcls;
        out[2] = liou;
        out[3] = ldfl;
    }
}

extern "C" void kernel_launch(void* const* d_in, const int* in_sizes, int n_in,
                              void* d_out, int out_size, void* d_ws, size_t ws_size,
                              hipStream_t stream) {
    const float* cls = (const float*)d_in[0];
    const float* bdist = (const float*)d_in[1];
    const float* bdec = (const float*)d_in[2];
    const float* tgt = (const float*)d_in[3];
    const float* anc = (const float*)d_in[4];
    const float* strd = (const float*)d_in[5];
    int Nv = in_sizes[4] / 2;
    int Bv = in_sizes[3] / (MGT * 5);
    size_t nBN = (size_t)Bv * Nv;
    int gx = (Nv + 255) / 256;
    int nb = gx * Bv;
    long long total4 = (long long)nBN * (NCLS / 4);
    int ncb = 2048;
    if ((long long)ncb * 256 > total4) ncb = (int)((total4 + 255) / 256);

    char* base = (char*)d_ws;
    size_t off = 0;
    unsigned* selmask = (unsigned*)(base + off); off += nBN * 4;
    unsigned* pos_al = (unsigned*)(base + off); off += (size_t)Bv * MGT * 4;
    unsigned* pos_ov = (unsigned*)(base + off); off += (size_t)Bv * MGT * 4;
    size_t zbytes = off;  // region needing zero-init each call
    int* bestm = (int*)(base + off); off += nBN * 4;
    int* gtfv = (int*)(base + off); off += nBN * 4;
    float* amv = (float*)(base + off); off += nBN * 4;
    float* crvv = (float*)(base + off); off += nBN * 4;
    float* tvalv = (float*)(base + off); off += nBN * 4;
    int* tlabv = (int*)(base + off); off += nBN * 4;
    float* p_tss = (float*)(base + off); off += (size_t)nb * 4;
    float* p_iou = (float*)(base + off); off += (size_t)nb * 4;
    float* p_dfl = (float*)(base + off); off += (size_t)nb * 4;
    float* p_cls = (float*)(base + off); off += (size_t)ncb * 4;
    float* abuf = (float*)(base + off);
    size_t remain = (ws_size > off) ? (ws_size - off) : 0;
    int chunk = (int)(remain / (nBN * 4));
    if (chunk > MGT) chunk = MGT;
    if (chunk < 1) chunk = 1;

    hipMemsetAsync(selmask, 0, zbytes, stream);
    dim3 grid(gx, Bv);
    k_best<<<grid, 256, 0, stream>>>(bdec, tgt, bestm, Nv);
    for (int cs = 0; cs < MGT; cs += chunk) {
        int clen = (MGT - cs < chunk) ? (MGT - cs) : chunk;
        k_alignc<<<grid, 256, 0, stream>>>(cls, bdec, tgt, anc, abuf, cs, clen, Nv);
        k_topk<<<Bv * clen, 256, 0, stream>>>(abuf, selmask, cs, clen, Nv);
    }
    k_resolve<<<grid, 256, 0, stream>>>(cls, bdec, tgt, anc, selmask, bestm,
                                        gtfv, amv, crvv, pos_al, pos_ov, Nv);
    k_boxdfl<<<grid, 256, 0, stream>>>(bdist, tgt, anc, strd, gtfv, amv, crvv,
                                       pos_al, pos_ov, tvalv, tlabv,
                                       p_tss, p_iou, p_dfl, Nv);
    k_cls2<<<ncb, 256, 0, stream>>>(cls, tlabv, tvalv, p_cls, total4, ncb * 256);
    k_final<<<1, 256, 0, stream>>>(p_tss, p_iou, p_dfl, nb, p_cls, ncb,
                                   (float*)d_out, Bv);
}

// Round 7
// 193.002 us; speedup vs baseline: 1.8226x; 1.0926x over previous
//
#include <hip/hip_runtime.h>
#include <math.h>

#define MGT 32
#define NCLS 80
#define TEPS 1e-9f
#define CEPS 1e-7f

__device__ __forceinline__ float ciou_f(float ax1, float ay1, float ax2, float ay2,
                                        float bx1, float by1, float bx2, float by2) {
    // matches reference _ciou (b1 = a, b2 = b); bit-symmetric in (a,b)
    float w1 = ax2 - ax1, h1 = ay2 - ay1;
    float w2 = bx2 - bx1, h2 = by2 - by1;
    float iw = fmaxf(fminf(ax2, bx2) - fmaxf(ax1, bx1), 0.f);
    float ih = fmaxf(fminf(ay2, by2) - fmaxf(ay1, by1), 0.f);
    float inter = iw * ih;
    float uni = w1 * h1 + w2 * h2 - inter + CEPS;
    float iou = inter / uni;
    float cw = fmaxf(ax2, bx2) - fminf(ax1, bx1);
    float ch = fmaxf(ay2, by2) - fminf(ay1, by1);
    float c2 = cw * cw + ch * ch + CEPS;
    float dx = bx1 + bx2 - ax1 - ax2;
    float dy = by1 + by2 - ay1 - ay2;
    float rho2 = (dx * dx + dy * dy) * 0.25f;
    float dv = atanf(w2 / (h2 + CEPS)) - atanf(w1 / (h1 + CEPS));
    float v = 0.405284734569351f * dv * dv;  // 4/pi^2
    float alpha = v / (v - iou + (1.f + CEPS));
    return iou - (rho2 / c2 + v * alpha);
}

__device__ __forceinline__ float sigm_fast(float x) {
    return __builtin_amdgcn_rcpf(1.f + __expf(-x));
}

// ---- fused: best-gt argmax + align metric for all 32 gts + zero-init ----
__global__ __launch_bounds__(256) void k_bestalign(const float* __restrict__ cls,
                                                   const float* __restrict__ bdec,
                                                   const float* __restrict__ tgt,
                                                   const float* __restrict__ anc,
                                                   float* __restrict__ abuf,
                                                   int* __restrict__ bestm,
                                                   unsigned* __restrict__ selmask,
                                                   unsigned* __restrict__ pos_al,
                                                   unsigned* __restrict__ pos_ov,
                                                   int Nv) {
    __shared__ float sx1[MGT], sy1[MGT], sx2[MGT], sy2[MGT];
    __shared__ int slab[MGT], svld[MGT];
    int b = blockIdx.y, tid = threadIdx.x;
    if (tid < MGT) {
        const float* t = tgt + ((size_t)b * MGT + tid) * 5;
        float lf = t[0];
        float x1 = t[1], y1 = t[2], x2 = t[3], y2 = t[4];
        sx1[tid] = x1; sy1[tid] = y1; sx2[tid] = x2; sy2[tid] = y2;
        float area = fmaxf(x2 - x1, 0.f) * fmaxf(y2 - y1, 0.f);
        int lab = (int)lf;
        svld[tid] = (lab >= 0 && area > 0.f) ? 1 : 0;
        slab[tid] = lab < 0 ? 0 : lab;
        if (blockIdx.x == 0) {  // zero pos maxes once per batch-row
            pos_al[b * MGT + tid] = 0u;
            pos_ov[b * MGT + tid] = 0u;
        }
    }
    __syncthreads();
    int n = blockIdx.x * 256 + tid;
    if (n >= Nv) return;
    size_t bn = (size_t)b * Nv + n;
    selmask[bn] = 0u;  // zeroed before k_topk ORs into it (stream-ordered)
    float4 p = reinterpret_cast<const float4*>(bdec)[bn];
    float2 a = reinterpret_cast<const float2*>(anc)[n];
    const float* crow = cls + bn * NCLS;
    float bo = -1.f; int bi = 0;
    for (int m = 0; m < MGT; ++m) {
        float ov = fmaxf(ciou_f(sx1[m], sy1[m], sx2[m], sy2[m],
                                p.x, p.y, p.z, p.w), 0.f);
        if (ov > bo) { bo = ov; bi = m; }  // first-max tiebreak
        float al = 0.f;
        if (svld[m]) {
            float mn = fminf(fminf(a.x - sx1[m], a.y - sy1[m]),
                             fminf(sx2[m] - a.x, sy2[m] - a.y));
            if (mn > TEPS && ov > 0.f) {
                float s = sigm_fast(crow[slab[m]]);
                float o2 = ov * ov;
                al = __builtin_sqrtf(s) * o2 * o2 * o2;  // s^0.5 * ov^6
            }
        }
        abuf[((size_t)b * MGT + m) * Nv + n] = al;
    }
    bestm[bn] = bi;
}

// ---- kernel: best gt per anchor (fallback path when ws too small) ----
__global__ __launch_bounds__(256) void k_best(const float* __restrict__ bdec,
                                              const float* __restrict__ tgt,
                                              int* __restrict__ bestm, int Nv) {
    __shared__ float sx1[MGT], sy1[MGT], sx2[MGT], sy2[MGT];
    int b = blockIdx.y, tid = threadIdx.x;
    if (tid < MGT) {
        const float* t = tgt + ((size_t)b * MGT + tid) * 5;
        sx1[tid] = t[1]; sy1[tid] = t[2]; sx2[tid] = t[3]; sy2[tid] = t[4];
    }
    __syncthreads();
    int n = blockIdx.x * 256 + tid;
    if (n >= Nv) return;
    size_t bn = (size_t)b * Nv + n;
    float4 p = reinterpret_cast<const float4*>(bdec)[bn];
    float bo = -1.f; int bi = 0;
    for (int m = 0; m < MGT; ++m) {
        float ov = fmaxf(ciou_f(sx1[m], sy1[m], sx2[m], sy2[m], p.x, p.y, p.z, p.w), 0.f);
        if (ov > bo) { bo = ov; bi = m; }
    }
    bestm[bn] = bi;
}

// ---- kernel: align metric for a chunk of gts (fallback path) ----
__global__ __launch_bounds__(256) void k_alignc(const float* __restrict__ cls,
                                                const float* __restrict__ bdec,
                                                const float* __restrict__ tgt,
                                                const float* __restrict__ anc,
                                                float* __restrict__ abuf,
                                                int cs, int clen, int Nv) {
    __shared__ float sx1[MGT], sy1[MGT], sx2[MGT], sy2[MGT];
    __shared__ int slab[MGT], svld[MGT];
    int b = blockIdx.y, tid = threadIdx.x;
    if (tid < MGT) {
        const float* t = tgt + ((size_t)b * MGT + tid) * 5;
        float lf = t[0];
        float x1 = t[1], y1 = t[2], x2 = t[3], y2 = t[4];
        sx1[tid] = x1; sy1[tid] = y1; sx2[tid] = x2; sy2[tid] = y2;
        float area = fmaxf(x2 - x1, 0.f) * fmaxf(y2 - y1, 0.f);
        int lab = (int)lf;
        svld[tid] = (lab >= 0 && area > 0.f) ? 1 : 0;
        slab[tid] = lab < 0 ? 0 : lab;
    }
    __syncthreads();
    int n = blockIdx.x * 256 + tid;
    if (n >= Nv) return;
    size_t bn = (size_t)b * Nv + n;
    float4 p = reinterpret_cast<const float4*>(bdec)[bn];
    float2 a = reinterpret_cast<const float2*>(anc)[n];
    const float* crow = cls + bn * NCLS;
    for (int mm = 0; mm < clen; ++mm) {
        int m = cs + mm;
        float al = 0.f;
        if (svld[m]) {
            float mn = fminf(fminf(a.x - sx1[m], a.y - sy1[m]),
                             fminf(sx2[m] - a.x, sy2[m] - a.y));
            if (mn > TEPS) {
                float ov = fmaxf(ciou_f(sx1[m], sy1[m], sx2[m], sy2[m],
                                        p.x, p.y, p.z, p.w), 0.f);
                if (ov > 0.f) {
                    float s = sigm_fast(crow[slab[m]]);
                    float o2 = ov * ov;
                    al = __builtin_sqrtf(s) * o2 * o2 * o2;
                }
            }
        }
        abuf[((size_t)b * clen + mm) * Nv + n] = al;
    }
}

// ---- kernel: per-(b,m) top-10 over N, set bit m in selmask for winners > EPS ----
__global__ __launch_bounds__(256) void k_topk(const float* __restrict__ abuf,
                                              unsigned* __restrict__ selmask,
                                              int cs, int clen, int Nv) {
    __shared__ float lv[2560];
    __shared__ int li[2560];
    __shared__ float rv[256];
    __shared__ int ri[256];
    int bmi = blockIdx.x;
    int b = bmi / clen, mm = bmi % clen;
    int m = cs + mm;
    int tid = threadIdx.x;
    const float* row = abuf + ((size_t)b * clen + mm) * Nv;
    float v[10]; int ix[10];
#pragma unroll
    for (int i = 0; i < 10; ++i) { v[i] = -1.f; ix[i] = 0x7fffffff; }
    for (int n = tid; n < Nv; n += 256) {
        float aa = row[n];
        if (aa > v[0]) {  // sorted ascending; equal -> keep earlier (lower idx)
            float cv = aa; int ci = n; bool placed = false;
#pragma unroll
            for (int i = 0; i < 9; ++i) {
                if (!placed) {
                    if (cv > v[i + 1]) { v[i] = v[i + 1]; ix[i] = ix[i + 1]; }
                    else { v[i] = cv; ix[i] = ci; placed = true; }
                }
            }
            if (!placed) { v[9] = cv; ix[9] = ci; }
        }
    }
#pragma unroll
    for (int i = 0; i < 10; ++i) { lv[tid * 10 + i] = v[i]; li[tid * 10 + i] = ix[i]; }
    int p = 9;
    for (int r = 0; r < 10; ++r) {
        float cv = (p >= 0) ? lv[tid * 10 + p] : -2.f;
        int ci = (p >= 0) ? li[tid * 10 + p] : -1;
        rv[tid] = cv; ri[tid] = ci;
        __syncthreads();
        for (int s = 128; s > 0; s >>= 1) {
            if (tid < s) {
                float o = rv[tid + s]; int oi = ri[tid + s];
                if (o > rv[tid] || (o == rv[tid] && oi < ri[tid])) { rv[tid] = o; ri[tid] = oi; }
            }
            __syncthreads();
        }
        float wv = rv[0]; int wi = ri[0];
        if (p >= 0 && cv == wv && ci == wi) --p;  // unique owner: indices disjoint
        if (tid == 0 && wv > TEPS) atomicOr(&selmask[(size_t)b * Nv + wi], 1u << m);
        __syncthreads();
    }
}

// ---- kernel: resolve multi-assignment, store per-anchor gt/align/ciou, pos maxes ----
__global__ __launch_bounds__(256) void k_resolve(const float* __restrict__ cls,
                                                 const float* __restrict__ bdec,
                                                 const float* __restrict__ tgt,
                                                 const float* __restrict__ anc,
                                                 const unsigned* __restrict__ selmask,
                                                 const int* __restrict__ bestm,
                                                 int* __restrict__ gtf,
                                                 float* __restrict__ amv,
                                                 float* __restrict__ crv,
                                                 unsigned* __restrict__ pos_al,
                                                 unsigned* __restrict__ pos_ov, int Nv) {
    __shared__ float sx1[MGT], sy1[MGT], sx2[MGT], sy2[MGT];
    __shared__ int slab[MGT], svld[MGT];
    int b = blockIdx.y, tid = threadIdx.x;
    if (tid < MGT) {
        const float* t = tgt + ((size_t)b * MGT + tid) * 5;
        float lf = t[0];
        float x1 = t[1], y1 = t[2], x2 = t[3], y2 = t[4];
        sx1[tid] = x1; sy1[tid] = y1; sx2[tid] = x2; sy2[tid] = y2;
        float area = fmaxf(x2 - x1, 0.f) * fmaxf(y2 - y1, 0.f);
        int lab = (int)lf;
        svld[tid] = (lab >= 0 && area > 0.f) ? 1 : 0;
        slab[tid] = lab < 0 ? 0 : lab;
    }
    __syncthreads();
    int n = blockIdx.x * 256 + tid;
    if (n >= Nv) return;
    size_t bn = (size_t)b * Nv + n;
    unsigned msk = selmask[bn];
    if (__popc(msk) > 1) msk = 1u << bestm[bn];  // multi -> is_best (unmasked argmax)
    if (!msk) { gtf[bn] = -1; amv[bn] = 0.f; crv[bn] = 0.f; return; }
    int g = __ffs(msk) - 1;
    float4 p = reinterpret_cast<const float4*>(bdec)[bn];
    float cr = ciou_f(sx1[g], sy1[g], sx2[g], sy2[g], p.x, p.y, p.z, p.w);
    float ov = fmaxf(cr, 0.f);
    float al = 0.f;
    if (svld[g]) {
        float2 a = reinterpret_cast<const float2*>(anc)[n];
        float mn = fminf(fminf(a.x - sx1[g], a.y - sy1[g]),
                         fminf(sx2[g] - a.x, sy2[g] - a.y));
        if (mn > TEPS && ov > 0.f) {
            float s = sigm_fast(cls[bn * NCLS + slab[g]]);
            float o2 = ov * ov;
            al = __builtin_sqrtf(s) * o2 * o2 * o2;
        }
    }
    gtf[bn] = g; amv[bn] = al; crv[bn] = cr;
    // nonneg floats: uint compare == float compare
    atomicMax(&pos_al[b * MGT + g], __float_as_uint(al));
    atomicMax(&pos_ov[b * MGT + g], __float_as_uint(ov));
}

// ---- kernel: norm (tval), tlab, tss, IoU loss, DFL loss partials ----
__global__ __launch_bounds__(256) void k_boxdfl(const float* __restrict__ bdist,
                                                const float* __restrict__ tgt,
                                                const float* __restrict__ anc,
                                                const float* __restrict__ strd,
                                                const int* __restrict__ gtf,
                                                const float* __restrict__ amv,
                                                const float* __restrict__ crv,
                                                const unsigned* __restrict__ pos_al,
                                                const unsigned* __restrict__ pos_ov,
                                                float* __restrict__ tval,
                                                int* __restrict__ tlabv,
                                                float* __restrict__ p_tss,
                                                float* __restrict__ p_iou,
                                                float* __restrict__ p_dfl, int Nv) {
    __shared__ float sx1[MGT], sy1[MGT], sx2[MGT], sy2[MGT];
    __shared__ int slab[MGT];
    __shared__ float r0[256], r1[256], r2[256];
    int b = blockIdx.y, tid = threadIdx.x;
    if (tid < MGT) {
        const float* t = tgt + ((size_t)b * MGT + tid) * 5;
        float lf = t[0];
        sx1[tid] = t[1]; sy1[tid] = t[2]; sx2[tid] = t[3]; sy2[tid] = t[4];
        slab[tid] = lf < 0.f ? 0 : (int)lf;
    }
    __syncthreads();
    int n = blockIdx.x * 256 + tid;
    float c_t = 0.f, c_i = 0.f, c_d = 0.f;
    if (n < Nv) {
        size_t bn = (size_t)b * Nv + n;
        int g = gtf[bn];
        float nv = 0.f;
        if (g >= 0) {
            float pa = __uint_as_float(pos_al[b * MGT + g]);
            float po = __uint_as_float(pos_ov[b * MGT + g]);
            nv = amv[bn] * po / (pa + TEPS);
        }
        tval[bn] = nv;
        tlabv[bn] = (g >= 0) ? slab[g] : -1;
        if (nv > 0.f) {
            c_t = nv;
            c_i = (1.f - crv[bn]) * nv;
            float2 a = reinterpret_cast<const float2*>(anc)[n];
            float st = strd[n];
            float ttv[4];
            ttv[0] = (a.x - sx1[g]) / st;
            ttv[1] = (a.y - sy1[g]) / st;
            ttv[2] = (sx2[g] - a.x) / st;
            ttv[3] = (sy2[g] - a.y) / st;
            const float* bd = bdist + bn * 64;
            float acc = 0.f;
#pragma unroll
            for (int k = 0; k < 4; ++k) {
                float t = fminf(fmaxf(ttv[k], 0.f), 14.99f);
                int tl = (int)t;
                float wl = (float)(tl + 1) - t;
                float mx = -3.4e38f;
                for (int j = 0; j < 16; ++j) mx = fmaxf(mx, bd[k * 16 + j]);
                float se = 0.f;
                for (int j = 0; j < 16; ++j) se += __expf(bd[k * 16 + j] - mx);
                float lse = mx + __logf(se);
                float ll = bd[k * 16 + tl] - lse;
                float lr = bd[k * 16 + tl + 1] - lse;
                acc += ll * wl + lr * (1.f - wl);
            }
            c_d = (-acc * 0.25f) * nv;
        }
    }
    r0[tid] = c_t; r1[tid] = c_i; r2[tid] = c_d;
    __syncthreads();
    for (int s = 128; s > 0; s >>= 1) {
        if (tid < s) { r0[tid] += r0[tid + s]; r1[tid] += r1[tid + s]; r2[tid] += r2[tid + s]; }
        __syncthreads();
    }
    if (tid == 0) {
        int bi = blockIdx.y * gridDim.x + blockIdx.x;
        p_tss[bi] = r0[0]; p_iou[bi] = r1[0]; p_dfl[bi] = r2[0];
    }
}

// ---- kernel: BCE classification loss, flat-linear coalesced, fast math ----
__global__ __launch_bounds__(256) void k_cls2(const float* __restrict__ cls,
                                              const int* __restrict__ tlabv,
                                              const float* __restrict__ tval,
                                              float* __restrict__ p_cls,
                                              int total4, int stride_t) {
    __shared__ float rs[256];
    float sum = 0.f;
    for (int i4 = blockIdx.x * 256 + threadIdx.x; i4 < total4; i4 += stride_t) {
        int bn = i4 / 20;  // 20 float4 per 80-class row
        int pos = i4 - bn * 20;
        float4 x4 = reinterpret_cast<const float4*>(cls)[i4];
        int tlab = tlabv[bn];
        float tv = tval[bn];
        int c0 = pos * 4;
        float xs[4] = {x4.x, x4.y, x4.z, x4.w};
#pragma unroll
        for (int e = 0; e < 4; ++e) {
            float x = xs[e];
            float ea = __expf(-fabsf(x));        // shared: sigmoid + log1p
            float r = __builtin_amdgcn_rcpf(1.f + ea);
            float p = (x >= 0.f) ? r : ea * r;   // sigmoid(x)
            float t = (c0 + e == tlab) ? tv : 0.f;
            float bce = fmaxf(x, 0.f) - x * t + __logf(1.f + ea);
            float w = (t > 0.f) ? t : 0.75f * p * p;
            sum += bce * w;
        }
    }
    rs[threadIdx.x] = sum;
    __syncthreads();
    for (int s = 128; s > 0; s >>= 1) {
        if (threadIdx.x < s) rs[threadIdx.x] += rs[threadIdx.x + s];
        __syncthreads();
    }
    if (threadIdx.x == 0) p_cls[blockIdx.x] = rs[0];
}

// ---- kernel: deterministic final reduce + combine ----
__global__ __launch_bounds__(256) void k_final(const float* __restrict__ p_tss,
                                               const float* __restrict__ p_iou,
                                               const float* __restrict__ p_dfl,
                                               int nb,
                                               const float* __restrict__ p_cls,
                                               int ncb, float* __restrict__ out, int Bv) {
    __shared__ float s0[256], s1[256], s2[256], s3[256];
    int tid = threadIdx.x;
    float a0 = 0.f, a1 = 0.f, a2 = 0.f, a3 = 0.f;
    for (int i = tid; i < nb; i += 256) {
        a0 += p_tss[i]; a1 += p_iou[i]; a2 += p_dfl[i];
    }
    for (int i = tid; i < ncb; i += 256) a3 += p_cls[i];
    s0[tid] = a0; s1[tid] = a1; s2[tid] = a2; s3[tid] = a3;
    __syncthreads();
    for (int s = 128; s > 0; s >>= 1) {
        if (tid < s) { s0[tid] += s0[tid + s]; s1[tid] += s1[tid + s];
                       s2[tid] += s2[tid + s]; s3[tid] += s3[tid + s]; }
        __syncthreads();
    }
    if (tid == 0) {
        float tss = fmaxf(s0[0], 1.f);
        float lcls = 0.5f * s3[0] / tss;
        float liou = 7.5f * s1[0] / tss;
        float ldfl = 1.5f * s2[0] / tss;
        out[0] = (lcls + liou + ldfl) * (float)Bv;
        out[1] = lcls;
        out[2] = liou;
        out[3] = ldfl;
    }
}

extern "C" void kernel_launch(void* const* d_in, const int* in_sizes, int n_in,
                              void* d_out, int out_size, void* d_ws, size_t ws_size,
                              hipStream_t stream) {
    const float* cls = (const float*)d_in[0];
    const float* bdist = (const float*)d_in[1];
    const float* bdec = (const float*)d_in[2];
    const float* tgt = (const float*)d_in[3];
    const float* anc = (const float*)d_in[4];
    const float* strd = (const float*)d_in[5];
    int Nv = in_sizes[4] / 2;
    int Bv = in_sizes[3] / (MGT * 5);
    size_t nBN = (size_t)Bv * Nv;
    int gx = (Nv + 255) / 256;
    int nb = gx * Bv;
    int total4 = (int)(nBN * (NCLS / 4));
    int ncb = 2048;
    if ((long long)ncb * 256 > (long long)total4) ncb = (total4 + 255) / 256;

    char* base = (char*)d_ws;
    size_t off = 0;
    unsigned* selmask = (unsigned*)(base + off); off += nBN * 4;
    unsigned* pos_al = (unsigned*)(base + off); off += (size_t)Bv * MGT * 4;
    unsigned* pos_ov = (unsigned*)(base + off); off += (size_t)Bv * MGT * 4;
    size_t zbytes = off;  // zero-init region (fallback path memset)
    int* bestm = (int*)(base + off); off += nBN * 4;
    int* gtfv = (int*)(base + off); off += nBN * 4;
    float* amv = (float*)(base + off); off += nBN * 4;
    float* crvv = (float*)(base + off); off += nBN * 4;
    float* tvalv = (float*)(base + off); off += nBN * 4;
    int* tlabv = (int*)(base + off); off += nBN * 4;
    float* p_tss = (float*)(base + off); off += (size_t)nb * 4;
    float* p_iou = (float*)(base + off); off += (size_t)nb * 4;
    float* p_dfl = (float*)(base + off); off += (size_t)nb * 4;
    float* p_cls = (float*)(base + off); off += (size_t)ncb * 4;
    float* abuf = (float*)(base + off);
    size_t remain = (ws_size > off) ? (ws_size - off) : 0;
    int chunk = (int)(remain / (nBN * 4));
    if (chunk > MGT) chunk = MGT;
    if (chunk < 1) chunk = 1;

    dim3 grid(gx, Bv);
    if (chunk == MGT) {
        // fused path: one CIoU sweep computes bestm + align; zero-init folded in
        k_bestalign<<<grid, 256, 0, stream>>>(cls, bdec, tgt, anc, abuf, bestm,
                                              selmask, pos_al, pos_ov, Nv);
        k_topk<<<Bv * MGT, 256, 0, stream>>>(abuf, selmask, 0, MGT, Nv);
    } else {
        hipMemsetAsync(selmask, 0, zbytes, stream);
        k_best<<<grid, 256, 0, stream>>>(bdec, tgt, bestm, Nv);
        for (int cs = 0; cs < MGT; cs += chunk) {
            int clen = (MGT - cs < chunk) ? (MGT - cs) : chunk;
            k_alignc<<<grid, 256, 0, stream>>>(cls, bdec, tgt, anc, abuf, cs, clen, Nv);
            k_topk<<<Bv * clen, 256, 0, stream>>>(abuf, selmask, cs, clen, Nv);
        }
    }
    k_resolve<<<grid, 256, 0, stream>>>(cls, bdec, tgt, anc, selmask, bestm,
                                        gtfv, amv, crvv, pos_al, pos_ov, Nv);
    k_boxdfl<<<grid, 256, 0, stream>>>(bdist, tgt, anc, strd, gtfv, amv, crvv,
                                       pos_al, pos_ov, tvalv, tlabv,
                                       p_tss, p_iou, p_dfl, Nv);
    k_cls2<<<ncb, 256, 0, stream>>>(cls, tlabv, tvalv, p_cls, total4, ncb * 256);
    k_final<<<1, 256, 0, stream>>>(p_tss, p_iou, p_dfl, nb, p_cls, ncb,
                                   (float*)d_out, Bv);
}

// Round 8
// 169.343 us; speedup vs baseline: 2.0772x; 1.1397x over previous
//
#include <hip/hip_runtime.h>
#include <math.h>

#define MGT 32
#define NCLS 80
#define TEPS 1e-9f
#define CEPS 1e-7f

__device__ __forceinline__ float ciou_f(float ax1, float ay1, float ax2, float ay2,
                                        float bx1, float by1, float bx2, float by2) {
    // matches reference _ciou (b1 = a, b2 = b); bit-symmetric in (a,b)
    float w1 = ax2 - ax1, h1 = ay2 - ay1;
    float w2 = bx2 - bx1, h2 = by2 - by1;
    float iw = fmaxf(fminf(ax2, bx2) - fmaxf(ax1, bx1), 0.f);
    float ih = fmaxf(fminf(ay2, by2) - fmaxf(ay1, by1), 0.f);
    float inter = iw * ih;
    float uni = w1 * h1 + w2 * h2 - inter + CEPS;
    float iou = inter / uni;
    float cw = fmaxf(ax2, bx2) - fminf(ax1, bx1);
    float ch = fmaxf(ay2, by2) - fminf(ay1, by1);
    float c2 = cw * cw + ch * ch + CEPS;
    float dx = bx1 + bx2 - ax1 - ax2;
    float dy = by1 + by2 - ay1 - ay2;
    float rho2 = (dx * dx + dy * dy) * 0.25f;
    float dv = atanf(w2 / (h2 + CEPS)) - atanf(w1 / (h1 + CEPS));
    float v = 0.405284734569351f * dv * dv;  // 4/pi^2
    float alpha = v / (v - iou + (1.f + CEPS));
    return iou - (rho2 / c2 + v * alpha);
}

// hoisted-precompute variant: awh=w1*h1, aatan=atan(w1/(h1+eps)) for box a (gt),
// bwh/batan likewise for box b (pred). Bit-identical to ciou_f.
__device__ __forceinline__ float ciou_pre(float ax1, float ay1, float ax2, float ay2,
                                          float awh, float aatan,
                                          float bx1, float by1, float bx2, float by2,
                                          float bwh, float batan) {
    float iw = fmaxf(fminf(ax2, bx2) - fmaxf(ax1, bx1), 0.f);
    float ih = fmaxf(fminf(ay2, by2) - fmaxf(ay1, by1), 0.f);
    float inter = iw * ih;
    float uni = awh + bwh - inter + CEPS;   // same assoc as w1*h1 + w2*h2 - inter + eps
    float iou = inter / uni;
    float cw = fmaxf(ax2, bx2) - fminf(ax1, bx1);
    float ch = fmaxf(ay2, by2) - fminf(ay1, by1);
    float c2 = cw * cw + ch * ch + CEPS;
    float dx = bx1 + bx2 - ax1 - ax2;
    float dy = by1 + by2 - ay1 - ay2;
    float rho2 = (dx * dx + dy * dy) * 0.25f;
    float dv = batan - aatan;               // atan(pred) - atan(gt), hoisted
    float v = 0.405284734569351f * dv * dv;
    float alpha = v / (v - iou + (1.f + CEPS));
    return iou - (rho2 / c2 + v * alpha);
}

__device__ __forceinline__ float sigm_fast(float x) {
    return __builtin_amdgcn_rcpf(1.f + __expf(-x));
}

// ---- fused: best-gt argmax + align metric for all 32 gts + zero-init ----
__global__ __launch_bounds__(256) void k_bestalign(const float* __restrict__ cls,
                                                   const float* __restrict__ bdec,
                                                   const float* __restrict__ tgt,
                                                   const float* __restrict__ anc,
                                                   float* __restrict__ abuf,
                                                   int* __restrict__ bestm,
                                                   unsigned* __restrict__ selmask,
                                                   unsigned* __restrict__ pos_al,
                                                   unsigned* __restrict__ pos_ov,
                                                   int Nv) {
    __shared__ float sx1[MGT], sy1[MGT], sx2[MGT], sy2[MGT];
    __shared__ float swh[MGT], satan[MGT];
    __shared__ int slab[MGT], svld[MGT];
    int b = blockIdx.y, tid = threadIdx.x;
    if (tid < MGT) {
        const float* t = tgt + ((size_t)b * MGT + tid) * 5;
        float lf = t[0];
        float x1 = t[1], y1 = t[2], x2 = t[3], y2 = t[4];
        sx1[tid] = x1; sy1[tid] = y1; sx2[tid] = x2; sy2[tid] = y2;
        float gw = x2 - x1, gh = y2 - y1;
        swh[tid] = gw * gh;
        satan[tid] = atanf(gw / (gh + CEPS));
        float area = fmaxf(gw, 0.f) * fmaxf(gh, 0.f);
        int lab = (int)lf;
        svld[tid] = (lab >= 0 && area > 0.f) ? 1 : 0;
        slab[tid] = lab < 0 ? 0 : lab;
        if (blockIdx.x == 0) {  // zero pos maxes once per batch-row
            pos_al[b * MGT + tid] = 0u;
            pos_ov[b * MGT + tid] = 0u;
        }
    }
    __syncthreads();
    int n = blockIdx.x * 256 + tid;
    if (n >= Nv) return;
    size_t bn = (size_t)b * Nv + n;
    selmask[bn] = 0u;  // zeroed before k_topk ORs into it (stream-ordered)
    float4 p = reinterpret_cast<const float4*>(bdec)[bn];
    float2 a = reinterpret_cast<const float2*>(anc)[n];
    const float* crow = cls + bn * NCLS;
    float pw = p.z - p.x, ph = p.w - p.y;
    float pwh = pw * ph;
    float patan = atanf(pw / (ph + CEPS));
    float bo = -1.f; int bi = 0;
    for (int m = 0; m < MGT; ++m) {
        float ov = fmaxf(ciou_pre(sx1[m], sy1[m], sx2[m], sy2[m], swh[m], satan[m],
                                  p.x, p.y, p.z, p.w, pwh, patan), 0.f);
        if (ov > bo) { bo = ov; bi = m; }  // first-max tiebreak
        float al = 0.f;
        if (svld[m]) {
            float mn = fminf(fminf(a.x - sx1[m], a.y - sy1[m]),
                             fminf(sx2[m] - a.x, sy2[m] - a.y));
            if (mn > TEPS && ov > 0.f) {
                float s = sigm_fast(crow[slab[m]]);
                float o2 = ov * ov;
                al = __builtin_sqrtf(s) * o2 * o2 * o2;  // s^0.5 * ov^6
            }
        }
        abuf[((size_t)b * MGT + m) * Nv + n] = al;
    }
    bestm[bn] = bi;
}

// ---- kernel: best gt per anchor (fallback path when ws too small) ----
__global__ __launch_bounds__(256) void k_best(const float* __restrict__ bdec,
                                              const float* __restrict__ tgt,
                                              int* __restrict__ bestm, int Nv) {
    __shared__ float sx1[MGT], sy1[MGT], sx2[MGT], sy2[MGT];
    int b = blockIdx.y, tid = threadIdx.x;
    if (tid < MGT) {
        const float* t = tgt + ((size_t)b * MGT + tid) * 5;
        sx1[tid] = t[1]; sy1[tid] = t[2]; sx2[tid] = t[3]; sy2[tid] = t[4];
    }
    __syncthreads();
    int n = blockIdx.x * 256 + tid;
    if (n >= Nv) return;
    size_t bn = (size_t)b * Nv + n;
    float4 p = reinterpret_cast<const float4*>(bdec)[bn];
    float bo = -1.f; int bi = 0;
    for (int m = 0; m < MGT; ++m) {
        float ov = fmaxf(ciou_f(sx1[m], sy1[m], sx2[m], sy2[m], p.x, p.y, p.z, p.w), 0.f);
        if (ov > bo) { bo = ov; bi = m; }
    }
    bestm[bn] = bi;
}

// ---- kernel: align metric for a chunk of gts (fallback path) ----
__global__ __launch_bounds__(256) void k_alignc(const float* __restrict__ cls,
                                                const float* __restrict__ bdec,
                                                const float* __restrict__ tgt,
                                                const float* __restrict__ anc,
                                                float* __restrict__ abuf,
                                                int cs, int clen, int Nv) {
    __shared__ float sx1[MGT], sy1[MGT], sx2[MGT], sy2[MGT];
    __shared__ int slab[MGT], svld[MGT];
    int b = blockIdx.y, tid = threadIdx.x;
    if (tid < MGT) {
        const float* t = tgt + ((size_t)b * MGT + tid) * 5;
        float lf = t[0];
        float x1 = t[1], y1 = t[2], x2 = t[3], y2 = t[4];
        sx1[tid] = x1; sy1[tid] = y1; sx2[tid] = x2; sy2[tid] = y2;
        float area = fmaxf(x2 - x1, 0.f) * fmaxf(y2 - y1, 0.f);
        int lab = (int)lf;
        svld[tid] = (lab >= 0 && area > 0.f) ? 1 : 0;
        slab[tid] = lab < 0 ? 0 : lab;
    }
    __syncthreads();
    int n = blockIdx.x * 256 + tid;
    if (n >= Nv) return;
    size_t bn = (size_t)b * Nv + n;
    float4 p = reinterpret_cast<const float4*>(bdec)[bn];
    float2 a = reinterpret_cast<const float2*>(anc)[n];
    const float* crow = cls + bn * NCLS;
    for (int mm = 0; mm < clen; ++mm) {
        int m = cs + mm;
        float al = 0.f;
        if (svld[m]) {
            float mn = fminf(fminf(a.x - sx1[m], a.y - sy1[m]),
                             fminf(sx2[m] - a.x, sy2[m] - a.y));
            if (mn > TEPS) {
                float ov = fmaxf(ciou_f(sx1[m], sy1[m], sx2[m], sy2[m],
                                        p.x, p.y, p.z, p.w), 0.f);
                if (ov > 0.f) {
                    float s = sigm_fast(crow[slab[m]]);
                    float o2 = ov * ov;
                    al = __builtin_sqrtf(s) * o2 * o2 * o2;
                }
            }
        }
        abuf[((size_t)b * clen + mm) * Nv + n] = al;
    }
}

// ---- kernel: per-(b,m) top-10 over N via u64 keys + wave shuffle reduce ----
// key = bits(val)<<32 | ~idx  (monotone for val>0): max-val, then min-idx tiebreak.
__global__ __launch_bounds__(256) void k_topk(const float* __restrict__ abuf,
                                              unsigned* __restrict__ selmask,
                                              int cs, int clen, int Nv) {
    __shared__ unsigned long long lv[2560];
    __shared__ unsigned long long warp_r[4];
    __shared__ unsigned long long winner_s;
    int bmi = blockIdx.x;
    int b = bmi / clen, mm = bmi % clen;
    int m = cs + mm;
    int tid = threadIdx.x;
    const float* row = abuf + ((size_t)b * clen + mm) * Nv;
    unsigned long long v[10];
#pragma unroll
    for (int i = 0; i < 10; ++i) v[i] = 0ull;
    for (int n = tid; n < Nv; n += 256) {
        float aa = row[n];
        if (aa > 0.f) {
            unsigned long long key =
                (((unsigned long long)__float_as_uint(aa)) << 32) |
                (unsigned)(0xFFFFFFFFu - (unsigned)n);
            if (key > v[0]) {  // sorted ascending insert
                unsigned long long cv = key; bool placed = false;
#pragma unroll
                for (int i = 0; i < 9; ++i) {
                    if (!placed) {
                        if (cv > v[i + 1]) { v[i] = v[i + 1]; }
                        else { v[i] = cv; placed = true; }
                    }
                }
                if (!placed) v[9] = cv;
            }
        }
    }
#pragma unroll
    for (int i = 0; i < 10; ++i) lv[tid * 10 + i] = v[i];
    __syncthreads();
    int p = 9;
    for (int r = 0; r < 10; ++r) {
        unsigned long long cand = (p >= 0) ? lv[tid * 10 + p] : 0ull;
        unsigned long long w = cand;
#pragma unroll
        for (int s = 32; s > 0; s >>= 1) {
            unsigned long long o = __shfl_xor(w, s, 64);
            w = (o > w) ? o : w;
        }
        if ((tid & 63) == 0) warp_r[tid >> 6] = w;
        __syncthreads();
        if (tid == 0) {
            unsigned long long ww = warp_r[0];
            ww = (warp_r[1] > ww) ? warp_r[1] : ww;
            ww = (warp_r[2] > ww) ? warp_r[2] : ww;
            ww = (warp_r[3] > ww) ? warp_r[3] : ww;
            winner_s = ww;
            float wv = __uint_as_float((unsigned)(ww >> 32));
            if (wv > TEPS) {
                unsigned wi = 0xFFFFFFFFu - (unsigned)(ww & 0xFFFFFFFFull);
                atomicOr(&selmask[(size_t)b * Nv + wi], 1u << m);
            }
        }
        __syncthreads();
        unsigned long long win = winner_s;
        if (p >= 0 && win != 0ull && cand == win) --p;  // unique owner (idx in key)
        __syncthreads();
    }
}

// ---- kernel: resolve multi-assignment, store per-anchor gt/align/ciou, pos maxes ----
__global__ __launch_bounds__(256) void k_resolve(const float* __restrict__ cls,
                                                 const float* __restrict__ bdec,
                                                 const float* __restrict__ tgt,
                                                 const float* __restrict__ anc,
                                                 const unsigned* __restrict__ selmask,
                                                 const int* __restrict__ bestm,
                                                 int* __restrict__ gtf,
                                                 float* __restrict__ amv,
                                                 float* __restrict__ crv,
                                                 unsigned* __restrict__ pos_al,
                                                 unsigned* __restrict__ pos_ov, int Nv) {
    __shared__ float sx1[MGT], sy1[MGT], sx2[MGT], sy2[MGT];
    __shared__ float swh[MGT], satan[MGT];
    __shared__ int slab[MGT], svld[MGT];
    int b = blockIdx.y, tid = threadIdx.x;
    if (tid < MGT) {
        const float* t = tgt + ((size_t)b * MGT + tid) * 5;
        float lf = t[0];
        float x1 = t[1], y1 = t[2], x2 = t[3], y2 = t[4];
        sx1[tid] = x1; sy1[tid] = y1; sx2[tid] = x2; sy2[tid] = y2;
        float gw = x2 - x1, gh = y2 - y1;
        swh[tid] = gw * gh;
        satan[tid] = atanf(gw / (gh + CEPS));
        float area = fmaxf(gw, 0.f) * fmaxf(gh, 0.f);
        int lab = (int)lf;
        svld[tid] = (lab >= 0 && area > 0.f) ? 1 : 0;
        slab[tid] = lab < 0 ? 0 : lab;
    }
    __syncthreads();
    int n = blockIdx.x * 256 + tid;
    if (n >= Nv) return;
    size_t bn = (size_t)b * Nv + n;
    unsigned msk = selmask[bn];
    if (__popc(msk) > 1) msk = 1u << bestm[bn];  // multi -> is_best (unmasked argmax)
    if (!msk) { gtf[bn] = -1; amv[bn] = 0.f; crv[bn] = 0.f; return; }
    int g = __ffs(msk) - 1;
    float4 p = reinterpret_cast<const float4*>(bdec)[bn];
    float pw = p.z - p.x, ph = p.w - p.y;
    float cr = ciou_pre(sx1[g], sy1[g], sx2[g], sy2[g], swh[g], satan[g],
                        p.x, p.y, p.z, p.w, pw * ph, atanf(pw / (ph + CEPS)));
    float ov = fmaxf(cr, 0.f);
    float al = 0.f;
    if (svld[g]) {
        float2 a = reinterpret_cast<const float2*>(anc)[n];
        float mn = fminf(fminf(a.x - sx1[g], a.y - sy1[g]),
                         fminf(sx2[g] - a.x, sy2[g] - a.y));
        if (mn > TEPS && ov > 0.f) {
            float s = sigm_fast(cls[bn * NCLS + slab[g]]);
            float o2 = ov * ov;
            al = __builtin_sqrtf(s) * o2 * o2 * o2;
        }
    }
    gtf[bn] = g; amv[bn] = al; crv[bn] = cr;
    // nonneg floats: uint compare == float compare
    atomicMax(&pos_al[b * MGT + g], __float_as_uint(al));
    atomicMax(&pos_ov[b * MGT + g], __float_as_uint(ov));
}

// ---- kernel: norm (tval), tlab, tss, IoU loss, DFL loss partials ----
__global__ __launch_bounds__(256) void k_boxdfl(const float* __restrict__ bdist,
                                                const float* __restrict__ tgt,
                                                const float* __restrict__ anc,
                                                const float* __restrict__ strd,
                                                const int* __restrict__ gtf,
                                                const float* __restrict__ amv,
                                                const float* __restrict__ crv,
                                                const unsigned* __restrict__ pos_al,
                                                const unsigned* __restrict__ pos_ov,
                                                float* __restrict__ tval,
                                                int* __restrict__ tlabv,
                                                float* __restrict__ p_tss,
                                                float* __restrict__ p_iou,
                                                float* __restrict__ p_dfl, int Nv) {
    __shared__ float sx1[MGT], sy1[MGT], sx2[MGT], sy2[MGT];
    __shared__ int slab[MGT];
    __shared__ float r0[256], r1[256], r2[256];
    int b = blockIdx.y, tid = threadIdx.x;
    if (tid < MGT) {
        const float* t = tgt + ((size_t)b * MGT + tid) * 5;
        float lf = t[0];
        sx1[tid] = t[1]; sy1[tid] = t[2]; sx2[tid] = t[3]; sy2[tid] = t[4];
        slab[tid] = lf < 0.f ? 0 : (int)lf;
    }
    __syncthreads();
    int n = blockIdx.x * 256 + tid;
    float c_t = 0.f, c_i = 0.f, c_d = 0.f;
    if (n < Nv) {
        size_t bn = (size_t)b * Nv + n;
        int g = gtf[bn];
        float nv = 0.f;
        if (g >= 0) {
            float pa = __uint_as_float(pos_al[b * MGT + g]);
            float po = __uint_as_float(pos_ov[b * MGT + g]);
            nv = amv[bn] * po / (pa + TEPS);
        }
        tval[bn] = nv;
        tlabv[bn] = (g >= 0) ? slab[g] : -1;
        if (nv > 0.f) {
            c_t = nv;
            c_i = (1.f - crv[bn]) * nv;
            float2 a = reinterpret_cast<const float2*>(anc)[n];
            float st = strd[n];
            float ttv[4];
            ttv[0] = (a.x - sx1[g]) / st;
            ttv[1] = (a.y - sy1[g]) / st;
            ttv[2] = (sx2[g] - a.x) / st;
            ttv[3] = (sy2[g] - a.y) / st;
            const float* bd = bdist + bn * 64;
            float acc = 0.f;
#pragma unroll
            for (int k = 0; k < 4; ++k) {
                float t = fminf(fmaxf(ttv[k], 0.f), 14.99f);
                int tl = (int)t;
                float wl = (float)(tl + 1) - t;
                float mx = -3.4e38f;
                for (int j = 0; j < 16; ++j) mx = fmaxf(mx, bd[k * 16 + j]);
                float se = 0.f;
                for (int j = 0; j < 16; ++j) se += __expf(bd[k * 16 + j] - mx);
                float lse = mx + __logf(se);
                float ll = bd[k * 16 + tl] - lse;
                float lr = bd[k * 16 + tl + 1] - lse;
                acc += ll * wl + lr * (1.f - wl);
            }
            c_d = (-acc * 0.25f) * nv;
        }
    }
    r0[tid] = c_t; r1[tid] = c_i; r2[tid] = c_d;
    __syncthreads();
    for (int s = 128; s > 0; s >>= 1) {
        if (tid < s) { r0[tid] += r0[tid + s]; r1[tid] += r1[tid + s]; r2[tid] += r2[tid + s]; }
        __syncthreads();
    }
    if (tid == 0) {
        int bi = blockIdx.y * gridDim.x + blockIdx.x;
        p_tss[bi] = r0[0]; p_iou[bi] = r1[0]; p_dfl[bi] = r2[0];
    }
}

// ---- kernel: BCE classification loss, flat-linear coalesced, fast math ----
__global__ __launch_bounds__(256) void k_cls2(const float* __restrict__ cls,
                                              const int* __restrict__ tlabv,
                                              const float* __restrict__ tval,
                                              float* __restrict__ p_cls,
                                              int total4, int stride_t) {
    __shared__ float rs[256];
    float sum = 0.f;
    for (int i4 = blockIdx.x * 256 + threadIdx.x; i4 < total4; i4 += stride_t) {
        int bn = i4 / 20;  // 20 float4 per 80-class row
        int pos = i4 - bn * 20;
        float4 x4 = reinterpret_cast<const float4*>(cls)[i4];
        int tlab = tlabv[bn];
        float tv = tval[bn];
        int c0 = pos * 4;
        float xs[4] = {x4.x, x4.y, x4.z, x4.w};
#pragma unroll
        for (int e = 0; e < 4; ++e) {
            float x = xs[e];
            float ea = __expf(-fabsf(x));        // shared: sigmoid + log1p
            float r = __builtin_amdgcn_rcpf(1.f + ea);
            float p = (x >= 0.f) ? r : ea * r;   // sigmoid(x)
            float t = (c0 + e == tlab) ? tv : 0.f;
            float bce = fmaxf(x, 0.f) - x * t + __logf(1.f + ea);
            float w = (t > 0.f) ? t : 0.75f * p * p;
            sum += bce * w;
        }
    }
    rs[threadIdx.x] = sum;
    __syncthreads();
    for (int s = 128; s > 0; s >>= 1) {
        if (threadIdx.x < s) rs[threadIdx.x] += rs[threadIdx.x + s];
        __syncthreads();
    }
    if (threadIdx.x == 0) p_cls[blockIdx.x] = rs[0];
}

// ---- kernel: deterministic final reduce + combine ----
__global__ __launch_bounds__(256) void k_final(const float* __restrict__ p_tss,
                                               const float* __restrict__ p_iou,
                                               const float* __restrict__ p_dfl,
                                               int nb,
                                               const float* __restrict__ p_cls,
                                               int ncb, float* __restrict__ out, int Bv) {
    __shared__ float s0[256], s1[256], s2[256], s3[256];
    int tid = threadIdx.x;
    float a0 = 0.f, a1 = 0.f, a2 = 0.f, a3 = 0.f;
    for (int i = tid; i < nb; i += 256) {
        a0 += p_tss[i]; a1 += p_iou[i]; a2 += p_dfl[i];
    }
    for (int i = tid; i < ncb; i += 256) a3 += p_cls[i];
    s0[tid] = a0; s1[tid] = a1; s2[tid] = a2; s3[tid] = a3;
    __syncthreads();
    for (int s = 128; s > 0; s >>= 1) {
        if (tid < s) { s0[tid] += s0[tid + s]; s1[tid] += s1[tid + s];
                       s2[tid] += s2[tid + s]; s3[tid] += s3[tid + s]; }
        __syncthreads();
    }
    if (tid == 0) {
        float tss = fmaxf(s0[0], 1.f);
        float lcls = 0.5f * s3[0] / tss;
        float liou = 7.5f * s1[0] / tss;
        float ldfl = 1.5f * s2[0] / tss;
        out[0] = (lcls + liou + ldfl) * (float)Bv;
        out[1] = lcls;
        out[2] = liou;
        out[3] = ldfl;
    }
}

extern "C" void kernel_launch(void* const* d_in, const int* in_sizes, int n_in,
                              void* d_out, int out_size, void* d_ws, size_t ws_size,
                              hipStream_t stream) {
    const float* cls = (const float*)d_in[0];
    const float* bdist = (const float*)d_in[1];
    const float* bdec = (const float*)d_in[2];
    const float* tgt = (const float*)d_in[3];
    const float* anc = (const float*)d_in[4];
    const float* strd = (const float*)d_in[5];
    int Nv = in_sizes[4] / 2;
    int Bv = in_sizes[3] / (MGT * 5);
    size_t nBN = (size_t)Bv * Nv;
    int gx = (Nv + 255) / 256;
    int nb = gx * Bv;
    int total4 = (int)(nBN * (NCLS / 4));
    int ncb = 2048;
    if ((long long)ncb * 256 > (long long)total4) ncb = (total4 + 255) / 256;

    char* base = (char*)d_ws;
    size_t off = 0;
    unsigned* selmask = (unsigned*)(base + off); off += nBN * 4;
    unsigned* pos_al = (unsigned*)(base + off); off += (size_t)Bv * MGT * 4;
    unsigned* pos_ov = (unsigned*)(base + off); off += (size_t)Bv * MGT * 4;
    size_t zbytes = off;  // zero-init region (fallback path memset)
    int* bestm = (int*)(base + off); off += nBN * 4;
    int* gtfv = (int*)(base + off); off += nBN * 4;
    float* amv = (float*)(base + off); off += nBN * 4;
    float* crvv = (float*)(base + off); off += nBN * 4;
    float* tvalv = (float*)(base + off); off += nBN * 4;
    int* tlabv = (int*)(base + off); off += nBN * 4;
    float* p_tss = (float*)(base + off); off += (size_t)nb * 4;
    float* p_iou = (float*)(base + off); off += (size_t)nb * 4;
    float* p_dfl = (float*)(base + off); off += (size_t)nb * 4;
    float* p_cls = (float*)(base + off); off += (size_t)ncb * 4;
    float* abuf = (float*)(base + off);
    size_t remain = (ws_size > off) ? (ws_size - off) : 0;
    int chunk = (int)(remain / (nBN * 4));
    if (chunk > MGT) chunk = MGT;
    if (chunk < 1) chunk = 1;

    dim3 grid(gx, Bv);
    if (chunk == MGT) {
        // fused path: one CIoU sweep computes bestm + align; zero-init folded in
        k_bestalign<<<grid, 256, 0, stream>>>(cls, bdec, tgt, anc, abuf, bestm,
                                              selmask, pos_al, pos_ov, Nv);
        k_topk<<<Bv * MGT, 256, 0, stream>>>(abuf, selmask, 0, MGT, Nv);
    } else {
        hipMemsetAsync(selmask, 0, zbytes, stream);
        k_best<<<grid, 256, 0, stream>>>(bdec, tgt, bestm, Nv);
        for (int cs = 0; cs < MGT; cs += chunk) {
            int clen = (MGT - cs < chunk) ? (MGT - cs) : chunk;
            k_alignc<<<grid, 256, 0, stream>>>(cls, bdec, tgt, anc, abuf, cs, clen, Nv);
            k_topk<<<Bv * clen, 256, 0, stream>>>(abuf, selmask, cs, clen, Nv);
        }
    }
    k_resolve<<<grid, 256, 0, stream>>>(cls, bdec, tgt, anc, selmask, bestm,
                                        gtfv, amv, crvv, pos_al, pos_ov, Nv);
    k_boxdfl<<<grid, 256, 0, stream>>>(bdist, tgt, anc, strd, gtfv, amv, crvv,
                                       pos_al, pos_ov, tvalv, tlabv,
                                       p_tss, p_iou, p_dfl, Nv);
    k_cls2<<<ncb, 256, 0, stream>>>(cls, tlabv, tvalv, p_cls, total4, ncb * 256);
    k_final<<<1, 256, 0, stream>>>(p_tss, p_iou, p_dfl, nb, p_cls, ncb,
                                   (float*)d_out, Bv);
}